// Round 1
// baseline (276.326 us; speedup 1.0000x reference)
//
#include <hip/hip_runtime.h>
#include <math.h>

#define NL 8
#define NP 512
#define NC 64
#define NF 128
#define NALL 192
#define NRAY (NL * NP)
#define HID 128

typedef _Float16 half8 __attribute__((ext_vector_type(8)));
typedef _Float16 half4v __attribute__((ext_vector_type(4)));
typedef float floatx16 __attribute__((ext_vector_type(16)));
typedef unsigned long long ull;

#define MFMA(a, b, c) __builtin_amdgcn_mfma_f32_32x32x16_f16((a), (b), (c), 0, 0, 0)

// r15 experiment: 64-pt blocks (was 128). Rationale from rocprof: MfmaUtil 40
// + VALUBusy 33 + LDS ~20 ~= 93% -> pipes serialized, not overlapped, because
// LDS 66.5KB allowed only 2 phase-locked blocks/CU (Occupancy 20.8%).
// Halving the H planes to 64x128 (33.3KB/block) gives 4 blocks/CU = 4
// independent barrier groups. Per-wave tile is now 64j x 32m (acc[2]); the
// 128-VGPR B-preload is replaced by per-ks LDS loads so we fit 4 waves/SIMD
// (__launch_bounds__(256,4)). Numerics identical: split-fp16 3-MFMA.

__device__ __forceinline__ float dcoarse_at(int i) {
    float t = (float)i * 0.015625f; // i/64, exact in fp32
    return 1e-3f * (1.0f - t) + 0.5f * t;
}

__device__ __forceinline__ floatx16 fzero16() {
    floatx16 z;
#pragma unroll
    for (int i = 0; i < 16; ++i) z[i] = 0.f;
    return z;
}
__device__ __forceinline__ half8 hzero8() {
    half8 z;
#pragma unroll
    for (int i = 0; i < 8; ++i) z[i] = (_Float16)0.f;
    return z;
}

// Wsp layout (per layer L in {0:w1, 1:w2}, plane p in {hi,lo}):
//   Wsp[(L*2+p)*16384 + f],  f = (((jb*8+ks)*2+lhi)*32 + l31)*8 + i
//   holding split(w[(ks*16+lhi*8+i)*128 + (jb*32+l31)]).
__global__ void prep_kernel(const float* __restrict__ w1, const float* __restrict__ w2,
                            _Float16* __restrict__ Wsp) {
    int f = blockIdx.x * 256 + threadIdx.x;   // [0, 16384)
    int layer = blockIdx.y;
    const float* w = layer ? w2 : w1;
    int i = f & 7, l31 = (f >> 3) & 31, lhi = (f >> 8) & 1, ks = (f >> 9) & 7, jb = f >> 12;
    int j = jb * 32 + l31;
    int k = ks * 16 + lhi * 8 + i;
    float v = w[k * 128 + j];
    _Float16 hi = (_Float16)v;
    Wsp[(layer * 2 + 0) * 16384 + f] = hi;
    Wsp[(layer * 2 + 1) * 16384 + f] = (_Float16)(v - (float)hi);
}

// Fused 4-layer MLP over 64 points per block, split-fp16 MFMA.
// MODE 0: coarse points (ray = pt>>6). MODE 1: fine points only (ray = pt>>7).
template<int MODE, int FASTW>
__global__ __launch_bounds__(256, 4) void mlp_kernel(
    const float* __restrict__ pts, const float* __restrict__ lights,
    const float* __restrict__ d_fine,
    const float* __restrict__ w0, const float* __restrict__ b0,
    const float* __restrict__ w1, const float* __restrict__ b1,
    const float* __restrict__ w2, const float* __restrict__ b2,
    const float* __restrict__ w3, const float* __restrict__ b3,
    const _Float16* __restrict__ Wsp,
    float* __restrict__ sdf_out)
{
    __shared__ __align__(16) _Float16 Hhi[64 * 128];
    __shared__ __align__(16) _Float16 Hlo[64 * 128];
    __shared__ _Float16 Xs[6 * 64];    // hi c0,c1,c2 then lo c0,c1,c2
    __shared__ float P2[2 * 64];       // [jh][m]

    const int tid = threadIdx.x;
    const int lane = tid & 63;
    const int wv = tid >> 6;
    const int jh = wv & 1, mh = wv >> 1;     // wave = (j-half, m-half of 32 pts)
    const int l31 = lane & 31, lhi = lane >> 5;
    const int base = blockIdx.x * 64;

    // ---- phase A: per-point coords, split to fp16 hi/lo in LDS
    if (tid < 64) {
        int pt = base + tid;
        int ray; float d;
        if (MODE == 0) { ray = pt >> 6; d = dcoarse_at(pt & 63); }
        else           { ray = pt >> 7; d = d_fine[pt]; }
        int l = ray >> 9, p = ray & (NP - 1);
        float px = pts[p * 3 + 0], py = pts[p * 3 + 1], pz = pts[p * 3 + 2];
        float dx = lights[l * 3 + 0] - px, dy = lights[l * 3 + 1] - py, dz = lights[l * 3 + 2] - pz;
        float n = sqrtf(dx * dx + dy * dy + dz * dz);
        dx /= n; dy /= n; dz /= n;
        float xc[3] = { px + d * dx, py + d * dy, pz + d * dz };
#pragma unroll
        for (int c = 0; c < 3; ++c) {
            _Float16 h = (_Float16)xc[c];
            Xs[c * 64 + tid] = h;
            Xs[(3 + c) * 64 + tid] = (_Float16)(xc[c] - (float)h);
        }
    }
    __syncthreads();

    const int m0 = mh * 32;                 // this wave's 32-pt half

    auto haddr = [&](int m, int k0) {
        return m * 128 + ((((k0 >> 3) ^ (m & 15)) << 3) | (k0 & 7));
    };

    auto store_tile = [&](const floatx16& a, int jt, const float* __restrict__ bias) {
        int m = m0 + l31;
#pragma unroll
        for (int g = 0; g < 4; ++g) {
            int jg = jh * 64 + jt * 32 + 8 * g + 4 * lhi;
            half4v hq, lq;
#pragma unroll
            for (int q = 0; q < 4; ++q) {
                float v = fmaxf(a[g * 4 + q] + bias[jg + q], 0.f);
                _Float16 hi = (_Float16)v;
                hq[q] = hi;
                lq[q] = (_Float16)(v - (float)hi);
            }
            int ad = haddr(m, jg);
            *(half4v*)&Hhi[ad] = hq;
            *(half4v*)&Hlo[ad] = lq;
        }
    };

    floatx16 acc[2];   // [jt] — 64j x 32m per wave

    // ---- Layer 1: 3->128 as one K=16 MFMA step (k>=3 zero-padded)
    {
        half8 a1h[2], a1l[2], bh1, bl1;
#pragma unroll
        for (int jt = 0; jt < 2; ++jt) { a1h[jt] = hzero8(); a1l[jt] = hzero8(); }
        bh1 = hzero8(); bl1 = hzero8();
        if (lhi == 0) {
#pragma unroll
            for (int jt = 0; jt < 2; ++jt) {
                int j = jh * 64 + jt * 32 + l31;
#pragma unroll
                for (int c = 0; c < 3; ++c) {
                    float v = w0[c * 128 + j];
                    _Float16 hi = (_Float16)v;
                    a1h[jt][c] = hi;
                    a1l[jt][c] = (_Float16)(v - (float)hi);
                }
            }
            int m = m0 + l31;
#pragma unroll
            for (int c = 0; c < 3; ++c) {
                bh1[c] = Xs[c * 64 + m];
                bl1[c] = Xs[(3 + c) * 64 + m];
            }
        }
#pragma unroll
        for (int jt = 0; jt < 2; ++jt) acc[jt] = fzero16();
#pragma unroll
        for (int jt = 0; jt < 2; ++jt) acc[jt] = MFMA(a1l[jt], bh1, acc[jt]);
#pragma unroll
        for (int jt = 0; jt < 2; ++jt) acc[jt] = MFMA(a1h[jt], bl1, acc[jt]);
#pragma unroll
        for (int jt = 0; jt < 2; ++jt) acc[jt] = MFMA(a1h[jt], bh1, acc[jt]);
#pragma unroll
        for (int jt = 0; jt < 2; ++jt) store_tile(acc[jt], jt, b0);
    }
    __syncthreads();   // H1 visible

    auto ldA = [&](int L, int jt, int ks, half8& ah, half8& al) {
        if (FASTW) {
            int off = ((((jh * 2 + jt) * 8 + ks) * 2 + lhi) * 32 + l31) * 8;
            ah = *(const half8*)&Wsp[(L * 2 + 0) * 16384 + off];
            al = *(const half8*)&Wsp[(L * 2 + 1) * 16384 + off];
        } else {
            const float* w = L ? w2 : w1;
            int j = jh * 64 + jt * 32 + l31, k0 = ks * 16 + lhi * 8;
#pragma unroll
            for (int i = 0; i < 8; ++i) {
                float v = w[(k0 + i) * 128 + j];
                _Float16 hi = (_Float16)v;
                ah[i] = hi;
                al[i] = (_Float16)(v - (float)hi);
            }
        }
    };

    // Per-ks B loads (no full preload): keeps VGPR under the 4-wave/SIMD cap;
    // LDS latency hidden by the 16 resident waves/CU.
    auto gemm = [&](int L) {
        const int m = m0 + l31;
#pragma unroll
        for (int jt = 0; jt < 2; ++jt) acc[jt] = fzero16();
#pragma unroll
        for (int ks = 0; ks < 8; ++ks) {
            int ad = haddr(m, ks * 16 + lhi * 8);
            half8 bh = *(const half8*)&Hhi[ad];
            half8 bl = *(const half8*)&Hlo[ad];
            half8 ah[2], al[2];
            ldA(L, 0, ks, ah[0], al[0]);
            ldA(L, 1, ks, ah[1], al[1]);
            acc[0] = MFMA(al[0], bh, acc[0]);
            acc[1] = MFMA(al[1], bh, acc[1]);
            acc[0] = MFMA(ah[0], bl, acc[0]);
            acc[1] = MFMA(ah[1], bl, acc[1]);
            acc[0] = MFMA(ah[0], bh, acc[0]);
            acc[1] = MFMA(ah[1], bh, acc[1]);
        }
    };

    // ---- Layer 2: H1 -> H2 (in place, barriered)
    gemm(0);
    __syncthreads();   // all waves done reading H1
#pragma unroll
    for (int jt = 0; jt < 2; ++jt) store_tile(acc[jt], jt, b1);
    __syncthreads();   // H2 visible

    // ---- Layer 3 (+ Layer 4 reduce, no write-back)
    gemm(1);
    {
        float p = 0.f;
#pragma unroll
        for (int jt = 0; jt < 2; ++jt)
#pragma unroll
            for (int g = 0; g < 4; ++g) {
                int jg = jh * 64 + jt * 32 + 8 * g + 4 * lhi;
#pragma unroll
                for (int q = 0; q < 4; ++q) {
                    float v = fmaxf(acc[jt][g * 4 + q] + b2[jg + q], 0.f);
                    p = fmaf(v, w3[jg + q], p);
                }
            }
        p += __shfl_xor(p, 32);
        if (lane < 32) P2[jh * 64 + m0 + l31] = p;
    }
    __syncthreads();
    if (tid < 64) sdf_out[base + tid] = b3[0] + P2[tid] + P2[64 + tid];
}

// One wave per ray: shfl scans for cdf, shfl binary-search for sample_pdf
// (exact searchsorted-count semantics on strictly-increasing cdf), then a
// 256-item bitonic KEY-VALUE sort (key = float-bits(d)<<32 | idx). Outputs
// raw fine d's (for the MLP) and the sorted provenance permutation.
__global__ __launch_bounds__(256) void sample_kernel(
    const float* __restrict__ sdf_c, const float* __restrict__ u,
    float* __restrict__ d_fine, unsigned char* __restrict__ perm8) {
    const int lane = threadIdx.x & 63, wv = threadIdx.x >> 6;
    const int ray = blockIdx.x * 4 + wv;

    float sv = sdf_c[ray * NC + lane];
    float c = 1.0f / (1.0f + expf(-100.0f * sv));
    float cn = __shfl_down(c, 1);
    bool valid = lane < 63;
    float a = valid ? fmaxf((c - cn) / (c + 1e-10f), 0.f) : 0.f;
    float sh = valid ? (1.f - a + 1e-10f) : 1.f;
    float ps = sh;
#pragma unroll
    for (int off = 1; off < 64; off <<= 1) { float o = __shfl_up(ps, off); if (lane >= off) ps *= o; }
    float T = __shfl_up(ps, 1);
    if (lane == 0) T = 1.f;
    float w = valid ? (a * T + 1e-5f) : 0.f;
    float wsum = w;
#pragma unroll
    for (int off = 1; off < 64; off <<= 1) wsum += __shfl_xor(wsum, off);
    float pdf = w / wsum;
    float cs = pdf;
#pragma unroll
    for (int off = 1; off < 64; off <<= 1) { float o = __shfl_up(cs, off); if (lane >= off) cs += o; }
    float cdfv = __shfl_up(cs, 1);
    if (lane == 0) cdfv = 0.f;    // cdf[lane], strictly increasing, cdf[0]=0

    float df[2];
#pragma unroll
    for (int t = 0; t < 2; ++t) {
        float uu = u[ray * NF + t * 64 + lane];
        int lo = 0;
#pragma unroll
        for (int b = 32; b >= 1; b >>= 1) {
            float cm = __shfl(cdfv, lo + b);
            if (uu >= cm) lo += b;
        }
        int above = min(lo + 1, NC - 1);
        float cb = __shfl(cdfv, lo), ca = __shfl(cdfv, above);
        float bb = dcoarse_at(lo), ba = dcoarse_at(above);
        float denom = ca - cb;
        if (denom < 1e-5f) denom = 1.f;
        float tt = (uu - cb) / denom;
        df[t] = bb + tt * (ba - bb);
        d_fine[ray * 128 + t * 64 + lane] = df[t];
    }

    ull v[4];
    v[0] = ((ull)__float_as_uint(dcoarse_at(lane)) << 32) | (unsigned)lane;
    v[1] = ((ull)__float_as_uint(df[0]) << 32) | (unsigned)(64 + lane);
    v[2] = ((ull)__float_as_uint(df[1]) << 32) | (unsigned)(128 + lane);
    v[3] = ((ull)0x7F800000u << 32) | 255u;   // +inf pad
    for (int k = 2; k <= 256; k <<= 1) {
        for (int j = k >> 1; j > 0; j >>= 1) {
            if (j >= 64) {
                int tj = j >> 6;
#pragma unroll
                for (int t = 0; t < 4; ++t) {
                    if ((t & tj) == 0) {
                        int t2 = t ^ tj;
                        bool asc = (((t * 64) & k) == 0);
                        ull x = v[t], y = v[t2];
                        bool sw = asc ? (x > y) : (x < y);
                        if (sw) { v[t] = y; v[t2] = x; }
                    }
                }
            } else {
#pragma unroll
                for (int t = 0; t < 4; ++t) {
                    int i = t * 64 + lane;
                    ull other = __shfl_xor(v[t], j);
                    bool lower = (lane & j) == 0;
                    bool asc = ((i & k) == 0);
                    bool takeMin = (lower == asc);
                    ull mn = v[t] < other ? v[t] : other;
                    ull mx = v[t] < other ? other : v[t];
                    v[t] = takeMin ? mn : mx;
                }
            }
        }
    }
#pragma unroll
    for (int t = 0; t < 3; ++t)
        perm8[ray * NALL + t * 64 + lane] = (unsigned char)(v[t] & 0xFFu);
}

// One wave per ray: gather sdf via permutation (idx<64 -> coarse, else fine),
// then chunked (3/lane) product scan for T, occu sum, out = 1-occu.
__global__ __launch_bounds__(256) void finish_kernel(
    const float* __restrict__ sdf_c, const float* __restrict__ sdf_f,
    const unsigned char* __restrict__ perm8, float* __restrict__ out) {
    int lane = threadIdx.x & 63, wv = threadIdx.x >> 6;
    int ray = blockIdx.x * 4 + wv;
    const unsigned char* P = perm8 + (size_t)ray * NALL;
    float c[4];
#pragma unroll
    for (int t = 0; t < 4; ++t) {
        int i = lane * 3 + t;
        if (i < NALL) {
            int idx = P[i];
            float s = (idx < 64) ? sdf_c[ray * NC + idx] : sdf_f[ray * 128 + (idx - 64)];
            c[t] = 1.0f / (1.0f + expf(-100.0f * s));
        } else c[t] = 0.f;
    }
    float a[3], s[3];
#pragma unroll
    for (int t = 0; t < 3; ++t) {
        int i = lane * 3 + t;
        if (i < NALL - 1) {
            a[t] = fmaxf((c[t] - c[t + 1]) / (c[t] + 1e-10f), 0.f);
            s[t] = 1.f - a[t] + 1e-10f;
        } else { a[t] = 0.f; s[t] = 1.f; }
    }
    float chunk = s[0] * s[1] * s[2];
    float ps = chunk;
#pragma unroll
    for (int off = 1; off < 64; off <<= 1) {
        float o = __shfl_up(ps, off);
        if (lane >= off) ps *= o;
    }
    float T = __shfl_up(ps, 1);
    if (lane == 0) T = 1.f;
    float occ = a[0] * T;
    T *= s[0]; occ = fmaf(a[1], T, occ);
    T *= s[1]; occ = fmaf(a[2], T, occ);
#pragma unroll
    for (int off = 1; off < 64; off <<= 1) occ += __shfl_xor(occ, off);
    if (lane == 0) out[ray] = 1.f - occ;
}

extern "C" void kernel_launch(void* const* d_in, const int* in_sizes, int n_in,
                              void* d_out, int out_size, void* d_ws, size_t ws_size,
                              hipStream_t stream) {
    const float* pts = (const float*)d_in[0];
    const float* lights = (const float*)d_in[1];
    const float* u = (const float*)d_in[2];
    const float* w0 = (const float*)d_in[3];
    const float* b0 = (const float*)d_in[4];
    const float* w1 = (const float*)d_in[5];
    const float* b1 = (const float*)d_in[6];
    const float* w2 = (const float*)d_in[7];
    const float* b2 = (const float*)d_in[8];
    const float* w3 = (const float*)d_in[9];
    const float* b3 = (const float*)d_in[10];
    float* out = (float*)d_out;

    // ws layout:
    //   sdf_c  : NRAY*64  f32   coarse sdf — persists to finish
    //   sdf_f  : NRAY*128 f32   fine sdf
    //   d_fine : NRAY*128 f32   raw fine sample depths
    //   perm8  : NRAY*192 u8    sorted provenance permutation
    //   Wsp    : 4*16384  f16   split weights
    char* wsb = (char*)d_ws;
    float* sdf_c = (float*)wsb;
    float* sdf_f = (float*)(wsb + (size_t)NRAY * NC * 4);
    float* d_fine = (float*)(wsb + (size_t)NRAY * (NC + 128) * 4);
    unsigned char* perm8 = (unsigned char*)(wsb + (size_t)NRAY * (NC + 256) * 4);
    _Float16* Wsp = (_Float16*)(wsb + (size_t)NRAY * (NC + 256) * 4 + (size_t)NRAY * NALL);
    const size_t need = (size_t)NRAY * (NC + 256) * 4 + (size_t)NRAY * NALL
                      + (size_t)4 * 16384 * sizeof(_Float16);
    const bool fast = ws_size >= need;

    if (fast) {
        prep_kernel<<<dim3(64, 2), 256, 0, stream>>>(w1, w2, Wsp);
        mlp_kernel<0, 1><<<(NRAY * NC) / 64, 256, 0, stream>>>(
            pts, lights, nullptr, w0, b0, w1, b1, w2, b2, w3, b3, Wsp, sdf_c);
        sample_kernel<<<NRAY / 4, 256, 0, stream>>>(sdf_c, u, d_fine, perm8);
        mlp_kernel<1, 1><<<(NRAY * 128) / 64, 256, 0, stream>>>(
            pts, lights, d_fine, w0, b0, w1, b1, w2, b2, w3, b3, Wsp, sdf_f);
    } else {
        mlp_kernel<0, 0><<<(NRAY * NC) / 64, 256, 0, stream>>>(
            pts, lights, nullptr, w0, b0, w1, b1, w2, b2, w3, b3, nullptr, sdf_c);
        sample_kernel<<<NRAY / 4, 256, 0, stream>>>(sdf_c, u, d_fine, perm8);
        mlp_kernel<1, 0><<<(NRAY * 128) / 64, 256, 0, stream>>>(
            pts, lights, d_fine, w0, b0, w1, b1, w2, b2, w3, b3, nullptr, sdf_f);
    }
    finish_kernel<<<NRAY / 4, 256, 0, stream>>>(sdf_c, sdf_f, perm8, out);
}

// Round 2
// 241.401 us; speedup vs baseline: 1.1447x; 1.1447x over previous
//
#include <hip/hip_runtime.h>
#include <math.h>

#define NL 8
#define NP 512
#define NC 64
#define NF 128
#define NALL 192
#define NRAY (NL * NP)
#define HID 128

typedef _Float16 half8 __attribute__((ext_vector_type(8)));
typedef _Float16 half4v __attribute__((ext_vector_type(4)));
typedef float floatx16 __attribute__((ext_vector_type(16)));
typedef unsigned long long ull;

#define MFMA(a, b, c) __builtin_amdgcn_mfma_f32_32x32x16_f16((a), (b), (c), 0, 0, 0)

// r16: 128-pt block (champion tile) split across 8 waves (512 thr) instead of 4.
// r15 post-mortem: 64-pt blocks doubled occupancy but ALSO doubled per-point
// fixed overhead + per-point weight traffic -> MfmaUtil fell. This keeps all
// per-point costs at champion parity (same H planes, same A duplication = 2x,
// same barrier count per 128 pts) while giving 4 waves/SIMD (2 blocks x 8 waves
// per CU) for cross-wave MFMA/VALU/LDS overlap. acc = 2 tiles (32 AGPR).
// Numerics: per-tile MFMA order byte-identical to champion; only the layer-4
// partial-sum association changes (4 quarter partials vs 2 half partials).

__device__ __forceinline__ float dcoarse_at(int i) {
    float t = (float)i * 0.015625f; // i/64, exact in fp32
    return 1e-3f * (1.0f - t) + 0.5f * t;
}

__device__ __forceinline__ floatx16 fzero16() {
    floatx16 z;
#pragma unroll
    for (int i = 0; i < 16; ++i) z[i] = 0.f;
    return z;
}
__device__ __forceinline__ half8 hzero8() {
    half8 z;
#pragma unroll
    for (int i = 0; i < 8; ++i) z[i] = (_Float16)0.f;
    return z;
}

// Wsp layout (per layer L in {0:w1, 1:w2}, plane p in {hi,lo}):
//   Wsp[(L*2+p)*16384 + f],  f = (((jb*8+ks)*2+lhi)*32 + l31)*8 + i
//   holding split(w[(ks*16+lhi*8+i)*128 + (jb*32+l31)]).
__global__ void prep_kernel(const float* __restrict__ w1, const float* __restrict__ w2,
                            _Float16* __restrict__ Wsp) {
    int f = blockIdx.x * 256 + threadIdx.x;   // [0, 16384)
    int layer = blockIdx.y;
    const float* w = layer ? w2 : w1;
    int i = f & 7, l31 = (f >> 3) & 31, lhi = (f >> 8) & 1, ks = (f >> 9) & 7, jb = f >> 12;
    int j = jb * 32 + l31;
    int k = ks * 16 + lhi * 8 + i;
    float v = w[k * 128 + j];
    _Float16 hi = (_Float16)v;
    Wsp[(layer * 2 + 0) * 16384 + f] = hi;
    Wsp[(layer * 2 + 1) * 16384 + f] = (_Float16)(v - (float)hi);
}

// Fused 4-layer MLP over 128 points per block, 8 waves, split-fp16 MFMA.
// MODE 0: coarse points (ray = pt>>6). MODE 1: fine points only (ray = pt>>7).
template<int MODE, int FASTW>
__global__ __launch_bounds__(512, 4) void mlp_kernel(
    const float* __restrict__ pts, const float* __restrict__ lights,
    const float* __restrict__ d_fine,
    const float* __restrict__ w0, const float* __restrict__ b0,
    const float* __restrict__ w1, const float* __restrict__ b1,
    const float* __restrict__ w2, const float* __restrict__ b2,
    const float* __restrict__ w3, const float* __restrict__ b3,
    const _Float16* __restrict__ Wsp,
    float* __restrict__ sdf_out)
{
    __shared__ __align__(16) _Float16 Hhi[128 * 128];
    __shared__ __align__(16) _Float16 Hlo[128 * 128];
    __shared__ _Float16 Xs[6 * 128];   // hi c0,c1,c2 then lo c0,c1,c2
    __shared__ float P2[4 * 128];      // [jq][m]

    const int tid = threadIdx.x;
    const int lane = tid & 63;
    const int wv = tid >> 6;                 // 0..7
    const int jq = wv & 3, mh = wv >> 2;     // j quarter (32 cols), m half (64 rows)
    const int l31 = lane & 31, lhi = lane >> 5;
    const int base = blockIdx.x * 128;

    // ---- phase A: per-point coords, split to fp16 hi/lo in LDS
    if (tid < 128) {
        int pt = base + tid;
        int ray; float d;
        if (MODE == 0) { ray = pt >> 6; d = dcoarse_at(pt & 63); }
        else           { ray = pt >> 7; d = d_fine[pt]; }
        int l = ray >> 9, p = ray & (NP - 1);
        float px = pts[p * 3 + 0], py = pts[p * 3 + 1], pz = pts[p * 3 + 2];
        float dx = lights[l * 3 + 0] - px, dy = lights[l * 3 + 1] - py, dz = lights[l * 3 + 2] - pz;
        float n = sqrtf(dx * dx + dy * dy + dz * dz);
        dx /= n; dy /= n; dz /= n;
        float xc[3] = { px + d * dx, py + d * dy, pz + d * dz };
#pragma unroll
        for (int c = 0; c < 3; ++c) {
            _Float16 h = (_Float16)xc[c];
            Xs[c * 128 + tid] = h;
            Xs[(3 + c) * 128 + tid] = (_Float16)(xc[c] - (float)h);
        }
    }
    __syncthreads();

    const int m0 = mh * 64;                 // this wave's 64-pt half

    auto haddr = [&](int m, int k0) {
        return m * 128 + ((((k0 >> 3) ^ (m & 15)) << 3) | (k0 & 7));
    };

    auto store_tile = [&](const floatx16& a, int mt, const float* __restrict__ bias) {
        int m = m0 + mt * 32 + l31;
#pragma unroll
        for (int g = 0; g < 4; ++g) {
            int jg = jq * 32 + 8 * g + 4 * lhi;
            half4v hq, lq;
#pragma unroll
            for (int q = 0; q < 4; ++q) {
                float v = fmaxf(a[g * 4 + q] + bias[jg + q], 0.f);
                _Float16 hi = (_Float16)v;
                hq[q] = hi;
                lq[q] = (_Float16)(v - (float)hi);
            }
            int ad = haddr(m, jg);
            *(half4v*)&Hhi[ad] = hq;
            *(half4v*)&Hlo[ad] = lq;
        }
    };

    floatx16 acc[2];   // [mt] — 32j x 64m per wave

    auto ldA = [&](int L, int ks, half8& ah, half8& al) {
        if (FASTW) {
            int off = (((jq * 8 + ks) * 2 + lhi) * 32 + l31) * 8;
            ah = *(const half8*)&Wsp[(L * 2 + 0) * 16384 + off];
            al = *(const half8*)&Wsp[(L * 2 + 1) * 16384 + off];
        } else {
            const float* w = L ? w2 : w1;
            int j = jq * 32 + l31, k0 = ks * 16 + lhi * 8;
#pragma unroll
            for (int i = 0; i < 8; ++i) {
                float v = w[(k0 + i) * 128 + j];
                _Float16 hi = (_Float16)v;
                ah[i] = hi;
                al[i] = (_Float16)(v - (float)hi);
            }
        }
    };

    // ---- Layer 1: 3->128 as one K=16 MFMA step (k>=3 zero-padded)
    {
        half8 a1h = hzero8(), a1l = hzero8(), bh1[2], bl1[2];
        bh1[0] = hzero8(); bh1[1] = hzero8(); bl1[0] = hzero8(); bl1[1] = hzero8();
        if (lhi == 0) {
            int j = jq * 32 + l31;
#pragma unroll
            for (int c = 0; c < 3; ++c) {
                float v = w0[c * 128 + j];
                _Float16 hi = (_Float16)v;
                a1h[c] = hi;
                a1l[c] = (_Float16)(v - (float)hi);
            }
#pragma unroll
            for (int mt = 0; mt < 2; ++mt) {
                int m = m0 + mt * 32 + l31;
#pragma unroll
                for (int c = 0; c < 3; ++c) {
                    bh1[mt][c] = Xs[c * 128 + m];
                    bl1[mt][c] = Xs[(3 + c) * 128 + m];
                }
            }
        }
        acc[0] = fzero16(); acc[1] = fzero16();
        acc[0] = MFMA(a1l, bh1[0], acc[0]); acc[1] = MFMA(a1l, bh1[1], acc[1]);
        acc[0] = MFMA(a1h, bl1[0], acc[0]); acc[1] = MFMA(a1h, bl1[1], acc[1]);
        acc[0] = MFMA(a1h, bh1[0], acc[0]); acc[1] = MFMA(a1h, bh1[1], acc[1]);
        store_tile(acc[0], 0, b0);
        store_tile(acc[1], 1, b0);
    }

    // Per-ks B loads; A streamed from Wsp; ks=0 A prefetched across barriers.
    auto gemm = [&](int L, half8 pa_h, half8 pa_l) {
        acc[0] = fzero16(); acc[1] = fzero16();
#pragma unroll
        for (int ks = 0; ks < 8; ++ks) {
            half8 ah, al;
            if (ks == 0) { ah = pa_h; al = pa_l; }
            else         ldA(L, ks, ah, al);
            half8 bh[2], bl[2];
#pragma unroll
            for (int mt = 0; mt < 2; ++mt) {
                int ad = haddr(m0 + mt * 32 + l31, ks * 16 + lhi * 8);
                bh[mt] = *(const half8*)&Hhi[ad];
                bl[mt] = *(const half8*)&Hlo[ad];
            }
            acc[0] = MFMA(al, bh[0], acc[0]); acc[1] = MFMA(al, bh[1], acc[1]);
            acc[0] = MFMA(ah, bl[0], acc[0]); acc[1] = MFMA(ah, bl[1], acc[1]);
            acc[0] = MFMA(ah, bh[0], acc[0]); acc[1] = MFMA(ah, bh[1], acc[1]);
        }
    };

    half8 pfh, pfl;
    ldA(0, 0, pfh, pfl);      // prefetch layer-2 ks=0 A (no LDS dependence)
    __syncthreads();   // H1 visible

    // ---- Layer 2: H1 -> H2 (in place, barriered)
    gemm(0, pfh, pfl);
    ldA(1, 0, pfh, pfl);      // prefetch layer-3 ks=0 A
    __syncthreads();   // all waves done reading H1
    store_tile(acc[0], 0, b1);
    store_tile(acc[1], 1, b1);
    __syncthreads();   // H2 visible

    // ---- Layer 3 (+ Layer 4 reduce, no write-back)
    gemm(1, pfh, pfl);
#pragma unroll
    for (int mt = 0; mt < 2; ++mt) {
        float p = 0.f;
#pragma unroll
        for (int g = 0; g < 4; ++g) {
            int jg = jq * 32 + 8 * g + 4 * lhi;
#pragma unroll
            for (int q = 0; q < 4; ++q) {
                float v = fmaxf(acc[mt][g * 4 + q] + b2[jg + q], 0.f);
                p = fmaf(v, w3[jg + q], p);
            }
        }
        p += __shfl_xor(p, 32);
        if (lane < 32) P2[jq * 128 + m0 + mt * 32 + l31] = p;
    }
    __syncthreads();
    if (tid < 128)
        sdf_out[base + tid] = b3[0] + P2[tid] + P2[128 + tid] + P2[256 + tid] + P2[384 + tid];
}

// One wave per ray: shfl scans for cdf, shfl binary-search for sample_pdf
// (exact searchsorted-count semantics on strictly-increasing cdf), then a
// 256-item bitonic KEY-VALUE sort (key = float-bits(d)<<32 | idx). Outputs
// raw fine d's (for the MLP) and the sorted provenance permutation.
__global__ __launch_bounds__(256) void sample_kernel(
    const float* __restrict__ sdf_c, const float* __restrict__ u,
    float* __restrict__ d_fine, unsigned char* __restrict__ perm8) {
    const int lane = threadIdx.x & 63, wv = threadIdx.x >> 6;
    const int ray = blockIdx.x * 4 + wv;

    float sv = sdf_c[ray * NC + lane];
    float c = 1.0f / (1.0f + expf(-100.0f * sv));
    float cn = __shfl_down(c, 1);
    bool valid = lane < 63;
    float a = valid ? fmaxf((c - cn) / (c + 1e-10f), 0.f) : 0.f;
    float sh = valid ? (1.f - a + 1e-10f) : 1.f;
    float ps = sh;
#pragma unroll
    for (int off = 1; off < 64; off <<= 1) { float o = __shfl_up(ps, off); if (lane >= off) ps *= o; }
    float T = __shfl_up(ps, 1);
    if (lane == 0) T = 1.f;
    float w = valid ? (a * T + 1e-5f) : 0.f;
    float wsum = w;
#pragma unroll
    for (int off = 1; off < 64; off <<= 1) wsum += __shfl_xor(wsum, off);
    float pdf = w / wsum;
    float cs = pdf;
#pragma unroll
    for (int off = 1; off < 64; off <<= 1) { float o = __shfl_up(cs, off); if (lane >= off) cs += o; }
    float cdfv = __shfl_up(cs, 1);
    if (lane == 0) cdfv = 0.f;    // cdf[lane], strictly increasing, cdf[0]=0

    float df[2];
#pragma unroll
    for (int t = 0; t < 2; ++t) {
        float uu = u[ray * NF + t * 64 + lane];
        int lo = 0;
#pragma unroll
        for (int b = 32; b >= 1; b >>= 1) {
            float cm = __shfl(cdfv, lo + b);
            if (uu >= cm) lo += b;
        }
        int above = min(lo + 1, NC - 1);
        float cb = __shfl(cdfv, lo), ca = __shfl(cdfv, above);
        float bb = dcoarse_at(lo), ba = dcoarse_at(above);
        float denom = ca - cb;
        if (denom < 1e-5f) denom = 1.f;
        float tt = (uu - cb) / denom;
        df[t] = bb + tt * (ba - bb);
        d_fine[ray * 128 + t * 64 + lane] = df[t];
    }

    ull v[4];
    v[0] = ((ull)__float_as_uint(dcoarse_at(lane)) << 32) | (unsigned)lane;
    v[1] = ((ull)__float_as_uint(df[0]) << 32) | (unsigned)(64 + lane);
    v[2] = ((ull)__float_as_uint(df[1]) << 32) | (unsigned)(128 + lane);
    v[3] = ((ull)0x7F800000u << 32) | 255u;   // +inf pad
    for (int k = 2; k <= 256; k <<= 1) {
        for (int j = k >> 1; j > 0; j >>= 1) {
            if (j >= 64) {
                int tj = j >> 6;
#pragma unroll
                for (int t = 0; t < 4; ++t) {
                    if ((t & tj) == 0) {
                        int t2 = t ^ tj;
                        bool asc = (((t * 64) & k) == 0);
                        ull x = v[t], y = v[t2];
                        bool sw = asc ? (x > y) : (x < y);
                        if (sw) { v[t] = y; v[t2] = x; }
                    }
                }
            } else {
#pragma unroll
                for (int t = 0; t < 4; ++t) {
                    int i = t * 64 + lane;
                    ull other = __shfl_xor(v[t], j);
                    bool lower = (lane & j) == 0;
                    bool asc = ((i & k) == 0);
                    bool takeMin = (lower == asc);
                    ull mn = v[t] < other ? v[t] : other;
                    ull mx = v[t] < other ? other : v[t];
                    v[t] = takeMin ? mn : mx;
                }
            }
        }
    }
#pragma unroll
    for (int t = 0; t < 3; ++t)
        perm8[ray * NALL + t * 64 + lane] = (unsigned char)(v[t] & 0xFFu);
}

// One wave per ray: gather sdf via permutation (idx<64 -> coarse, else fine),
// then chunked (3/lane) product scan for T, occu sum, out = 1-occu.
__global__ __launch_bounds__(256) void finish_kernel(
    const float* __restrict__ sdf_c, const float* __restrict__ sdf_f,
    const unsigned char* __restrict__ perm8, float* __restrict__ out) {
    int lane = threadIdx.x & 63, wv = threadIdx.x >> 6;
    int ray = blockIdx.x * 4 + wv;
    const unsigned char* P = perm8 + (size_t)ray * NALL;
    float c[4];
#pragma unroll
    for (int t = 0; t < 4; ++t) {
        int i = lane * 3 + t;
        if (i < NALL) {
            int idx = P[i];
            float s = (idx < 64) ? sdf_c[ray * NC + idx] : sdf_f[ray * 128 + (idx - 64)];
            c[t] = 1.0f / (1.0f + expf(-100.0f * s));
        } else c[t] = 0.f;
    }
    float a[3], s[3];
#pragma unroll
    for (int t = 0; t < 3; ++t) {
        int i = lane * 3 + t;
        if (i < NALL - 1) {
            a[t] = fmaxf((c[t] - c[t + 1]) / (c[t] + 1e-10f), 0.f);
            s[t] = 1.f - a[t] + 1e-10f;
        } else { a[t] = 0.f; s[t] = 1.f; }
    }
    float chunk = s[0] * s[1] * s[2];
    float ps = chunk;
#pragma unroll
    for (int off = 1; off < 64; off <<= 1) {
        float o = __shfl_up(ps, off);
        if (lane >= off) ps *= o;
    }
    float T = __shfl_up(ps, 1);
    if (lane == 0) T = 1.f;
    float occ = a[0] * T;
    T *= s[0]; occ = fmaf(a[1], T, occ);
    T *= s[1]; occ = fmaf(a[2], T, occ);
#pragma unroll
    for (int off = 1; off < 64; off <<= 1) occ += __shfl_xor(occ, off);
    if (lane == 0) out[ray] = 1.f - occ;
}

extern "C" void kernel_launch(void* const* d_in, const int* in_sizes, int n_in,
                              void* d_out, int out_size, void* d_ws, size_t ws_size,
                              hipStream_t stream) {
    const float* pts = (const float*)d_in[0];
    const float* lights = (const float*)d_in[1];
    const float* u = (const float*)d_in[2];
    const float* w0 = (const float*)d_in[3];
    const float* b0 = (const float*)d_in[4];
    const float* w1 = (const float*)d_in[5];
    const float* b1 = (const float*)d_in[6];
    const float* w2 = (const float*)d_in[7];
    const float* b2 = (const float*)d_in[8];
    const float* w3 = (const float*)d_in[9];
    const float* b3 = (const float*)d_in[10];
    float* out = (float*)d_out;

    // ws layout:
    //   sdf_c  : NRAY*64  f32   coarse sdf — persists to finish
    //   sdf_f  : NRAY*128 f32   fine sdf
    //   d_fine : NRAY*128 f32   raw fine sample depths
    //   perm8  : NRAY*192 u8    sorted provenance permutation
    //   Wsp    : 4*16384  f16   split weights
    char* wsb = (char*)d_ws;
    float* sdf_c = (float*)wsb;
    float* sdf_f = (float*)(wsb + (size_t)NRAY * NC * 4);
    float* d_fine = (float*)(wsb + (size_t)NRAY * (NC + 128) * 4);
    unsigned char* perm8 = (unsigned char*)(wsb + (size_t)NRAY * (NC + 256) * 4);
    _Float16* Wsp = (_Float16*)(wsb + (size_t)NRAY * (NC + 256) * 4 + (size_t)NRAY * NALL);
    const size_t need = (size_t)NRAY * (NC + 256) * 4 + (size_t)NRAY * NALL
                      + (size_t)4 * 16384 * sizeof(_Float16);
    const bool fast = ws_size >= need;

    if (fast) {
        prep_kernel<<<dim3(64, 2), 256, 0, stream>>>(w1, w2, Wsp);
        mlp_kernel<0, 1><<<(NRAY * NC) / 128, 512, 0, stream>>>(
            pts, lights, nullptr, w0, b0, w1, b1, w2, b2, w3, b3, Wsp, sdf_c);
        sample_kernel<<<NRAY / 4, 256, 0, stream>>>(sdf_c, u, d_fine, perm8);
        mlp_kernel<1, 1><<<(NRAY * 128) / 128, 512, 0, stream>>>(
            pts, lights, d_fine, w0, b0, w1, b1, w2, b2, w3, b3, Wsp, sdf_f);
    } else {
        mlp_kernel<0, 0><<<(NRAY * NC) / 128, 512, 0, stream>>>(
            pts, lights, nullptr, w0, b0, w1, b1, w2, b2, w3, b3, nullptr, sdf_c);
        sample_kernel<<<NRAY / 4, 256, 0, stream>>>(sdf_c, u, d_fine, perm8);
        mlp_kernel<1, 0><<<(NRAY * 128) / 128, 512, 0, stream>>>(
            pts, lights, d_fine, w0, b0, w1, b1, w2, b2, w3, b3, nullptr, sdf_f);
    }
    finish_kernel<<<NRAY / 4, 256, 0, stream>>>(sdf_c, sdf_f, perm8, out);
}